// Round 4
// baseline (681.736 us; speedup 1.0000x reference)
//
#include <hip/hip_runtime.h>
#include <hip/hip_bf16.h>
#include <math.h>

#define NN   20000
#define NE   640000
#define HD   128
#define EDIM 16
#define KIN  273    // 2H + 1 + ED
#define KP1  288    // KIN padded to 9*32
#define P1   296    // e_in LDS pitch (ushorts)
#define P2   136    // t1/m LDS pitch (ushorts)
#define PR   69     // pRed pitch (dwords)
#define SEG  79     // scan segment: 256*79 >= NN

typedef __bf16 bf16x8 __attribute__((ext_vector_type(8)));
typedef float  f32x4  __attribute__((ext_vector_type(4)));

__device__ __forceinline__ float silu_f(float v) {
    const float e = __expf(-v);
    return v * __builtin_amdgcn_rcpf(1.0f + e);
}
__device__ __forceinline__ float tanh_f(float s) {
    const float e = __expf(2.0f * s);
    return 1.0f - 2.0f * __builtin_amdgcn_rcpf(e + 1.0f);
}
__device__ __forceinline__ unsigned short f2bf(float f) {
    __bf16 b = (__bf16)f;
    return __builtin_bit_cast(unsigned short, b);
}
__device__ __forceinline__ float bf2f(unsigned short u) {
    __bf16 b = __builtin_bit_cast(__bf16, u);
    return (float)b;
}

// -------------------- Prep: h->bf16, pack W into MFMA B-frag order ----------
__device__ __forceinline__ void pack_one(const float* __restrict__ W, int Kreal,
                                         unsigned short* __restrict__ P, int idx) {
    const int f    = idx >> 9;
    const int r    = idx & 511;
    const int lane = r >> 3;
    const int j    = r & 7;
    const int kb   = f >> 3;
    const int nb   = f & 7;
    const int k    = kb * 32 + (lane >> 4) * 8 + j;
    const int n    = nb * 16 + (lane & 15);
    const float v  = (k < Kreal) ? W[(size_t)k * HD + n] : 0.0f;
    P[idx] = f2bf(v);
}

__global__ void egnn_prep_kernel(
    const float* __restrict__ h,
    const float* __restrict__ We1, const float* __restrict__ We2,
    const float* __restrict__ Wx1,
    unsigned short* __restrict__ hb,
    unsigned short* __restrict__ PWe1, unsigned short* __restrict__ PWe2,
    unsigned short* __restrict__ PWx1)
{
    const size_t NH = (size_t)NN * HD;
    const size_t S1 = (size_t)(KP1 / 32) * 8 * 512;
    const size_t S2 = (size_t)4 * 8 * 512;
    const size_t S3 = S2;
    const size_t total  = NH + S1 + S2 + S3;
    const size_t stride = (size_t)gridDim.x * blockDim.x;
    for (size_t i = (size_t)blockIdx.x * blockDim.x + threadIdx.x; i < total; i += stride) {
        if (i < NH) {
            hb[i] = f2bf(h[i]);
        } else if (i < NH + S1) {
            pack_one(We1, KIN, PWe1, (int)(i - NH));
        } else if (i < NH + S1 + S2) {
            pack_one(We2, HD, PWe2, (int)(i - NH - S1));
        } else {
            pack_one(Wx1, HD, PWx1, (int)(i - NH - S1 - S2));
        }
    }
}

// -------------------- Counting sort by dst --------------------
__global__ void egnn_hist_kernel(const int* __restrict__ ei, int* __restrict__ cnt) {
    const int e = blockIdx.x * 256 + threadIdx.x;   // grid exactly NE
    atomicAdd(&cnt[ei[NE + e]], 1);
}

// single block: exclusive prefix sum of cnt[0..NN) -> cursor
__global__ void egnn_scan_kernel(const int* __restrict__ cnt, int* __restrict__ cursor) {
    __shared__ int ls[256];
    const int t = threadIdx.x;
    const int base = t * SEG;
    int s = 0;
    for (int i = 0; i < SEG; ++i) {
        const int idx = base + i;
        if (idx < NN) s += cnt[idx];
    }
    ls[t] = s;
    __syncthreads();
    int v = s;
    for (int off = 1; off < 256; off <<= 1) {
        const int u = (t >= off) ? ls[t - off] : 0;
        __syncthreads();
        v += u;
        ls[t] = v;
        __syncthreads();
    }
    int run = v - s;   // exclusive base of this segment
    for (int i = 0; i < SEG; ++i) {
        const int idx = base + i;
        if (idx < NN) {
            cursor[idx] = run;
            run += cnt[idx];
        }
    }
}

__global__ void egnn_perm_kernel(const int* __restrict__ ei,
                                 int* __restrict__ cursor, int* __restrict__ perm) {
    const int e = blockIdx.x * 256 + threadIdx.x;
    const int d = ei[NE + e];
    const int pos = atomicAdd(&cursor[d], 1);
    perm[pos] = e;
}

// -------------------- Edge kernel (MFMA, dst-sorted edges) --------------------
__global__ __launch_bounds__(256, 2) void egnn_edge_kernel(
    const unsigned short* __restrict__ hb, const float* __restrict__ x,
    const int* __restrict__ ei, const float* __restrict__ eattr,
    const int* __restrict__ perm,
    const unsigned short* __restrict__ PWe1, const float* __restrict__ be1,
    const unsigned short* __restrict__ PWe2, const float* __restrict__ be2,
    const unsigned short* __restrict__ PWx1, const float* __restrict__ bx1,
    const float* __restrict__ Wx2, const float* __restrict__ bx2,
    float* __restrict__ msg_agg, float* __restrict__ coord_agg)
{
    __shared__ __align__(16) unsigned short eA[64 * P1];
    __shared__ __align__(16) unsigned short sT[64 * P2];
    __shared__ __align__(16) unsigned short sM[64 * P2];
    __shared__ int   sE[64], sSrc[64], sDst[64];
    __shared__ float sDiff[64][3];
    __shared__ float sDist[64];
    __shared__ float sW[64];

    const int t  = threadIdx.x;
    const int e0 = blockIdx.x * 64;

    if (t < 64) {
        const int e = perm[e0 + t];
        sE[t] = e;
        const int s = ei[e];
        const int d = ei[NE + e];
        sSrc[t] = s; sDst[t] = d;
        const float dx = x[s*3+0] - x[d*3+0];
        const float dy = x[s*3+1] - x[d*3+1];
        const float dz = x[s*3+2] - x[d*3+2];
        sDiff[t][0] = dx; sDiff[t][1] = dy; sDiff[t][2] = dz;
        sDist[t] = (dx*dx + dy*dy + dz*dz) * 0.01f;
    }
    __syncthreads();

    {
        const int eL = t >> 2, q = t & 3;
        const unsigned short* hs = hb + (size_t)sSrc[eL] * HD + q * 32;
        const unsigned short* hd = hb + (size_t)sDst[eL] * HD + q * 32;
        uint4* dsts = (uint4*)&eA[eL * P1 + q * 32];
        uint4* dstd = (uint4*)&eA[eL * P1 + 128 + q * 32];
        #pragma unroll
        for (int v = 0; v < 4; ++v) dsts[v] = ((const uint4*)hs)[v];
        #pragma unroll
        for (int v = 0; v < 4; ++v) dstd[v] = ((const uint4*)hd)[v];
        #pragma unroll
        for (int jj = 0; jj < 8; ++jj) {
            const int kg = 256 + q * 8 + jj;
            float v = 0.0f;
            if (kg == 256)     v = sDist[eL];
            else if (kg < KIN) v = eattr[(size_t)sE[eL] * EDIM + (kg - 257)];
            eA[eL * P1 + kg] = f2bf(v);
        }
    }
    __syncthreads();

    const int lane = t & 63;
    const int w    = t >> 6;
    const int quad = lane >> 4;
    const int l16  = lane & 15;

    // ---- GEMM1 ----
    f32x4 acc1[4][2];
    #pragma unroll
    for (int mb = 0; mb < 4; ++mb)
        #pragma unroll
        for (int nt = 0; nt < 2; ++nt) acc1[mb][nt] = (f32x4){0.f,0.f,0.f,0.f};

    for (int kb = 0; kb < 9; ++kb) {
        bf16x8 a[4], b[2];
        #pragma unroll
        for (int mb = 0; mb < 4; ++mb)
            a[mb] = *(const bf16x8*)&eA[(mb * 16 + l16) * P1 + kb * 32 + quad * 8];
        #pragma unroll
        for (int nt = 0; nt < 2; ++nt) {
            const int nb = w * 2 + nt;
            b[nt] = *(const bf16x8*)&PWe1[((kb * 8 + nb) * 64 + lane) * 8];
        }
        #pragma unroll
        for (int mb = 0; mb < 4; ++mb)
            #pragma unroll
            for (int nt = 0; nt < 2; ++nt)
                acc1[mb][nt] = __builtin_amdgcn_mfma_f32_16x16x32_bf16(
                    a[mb], b[nt], acc1[mb][nt], 0, 0, 0);
    }
    #pragma unroll
    for (int nt = 0; nt < 2; ++nt) {
        const int col = (w * 2 + nt) * 16 + l16;
        const float bias = be1[col];
        #pragma unroll
        for (int mb = 0; mb < 4; ++mb)
            #pragma unroll
            for (int r = 0; r < 4; ++r) {
                const int row = mb * 16 + quad * 4 + r;
                sT[row * P2 + col] = f2bf(silu_f(acc1[mb][nt][r] + bias));
            }
    }
    __syncthreads();

    // ---- GEMM2 ----
    f32x4 acc2[4][2];
    #pragma unroll
    for (int mb = 0; mb < 4; ++mb)
        #pragma unroll
        for (int nt = 0; nt < 2; ++nt) acc2[mb][nt] = (f32x4){0.f,0.f,0.f,0.f};
    for (int kb = 0; kb < 4; ++kb) {
        bf16x8 a[4], b[2];
        #pragma unroll
        for (int mb = 0; mb < 4; ++mb)
            a[mb] = *(const bf16x8*)&sT[(mb * 16 + l16) * P2 + kb * 32 + quad * 8];
        #pragma unroll
        for (int nt = 0; nt < 2; ++nt) {
            const int nb = w * 2 + nt;
            b[nt] = *(const bf16x8*)&PWe2[((kb * 8 + nb) * 64 + lane) * 8];
        }
        #pragma unroll
        for (int mb = 0; mb < 4; ++mb)
            #pragma unroll
            for (int nt = 0; nt < 2; ++nt)
                acc2[mb][nt] = __builtin_amdgcn_mfma_f32_16x16x32_bf16(
                    a[mb], b[nt], acc2[mb][nt], 0, 0, 0);
    }
    #pragma unroll
    for (int nt = 0; nt < 2; ++nt) {
        const int col = (w * 2 + nt) * 16 + l16;
        const float bias = be2[col];
        #pragma unroll
        for (int mb = 0; mb < 4; ++mb)
            #pragma unroll
            for (int r = 0; r < 4; ++r) {
                const int row = mb * 16 + quad * 4 + r;
                sM[row * P2 + col] = f2bf(silu_f(acc2[mb][nt][r] + bias));
            }
    }
    __syncthreads();

    // ---- GEMM3 + coord_w ----
    f32x4 acc3[4][2];
    #pragma unroll
    for (int mb = 0; mb < 4; ++mb)
        #pragma unroll
        for (int nt = 0; nt < 2; ++nt) acc3[mb][nt] = (f32x4){0.f,0.f,0.f,0.f};
    for (int kb = 0; kb < 4; ++kb) {
        bf16x8 a[4], b[2];
        #pragma unroll
        for (int mb = 0; mb < 4; ++mb)
            a[mb] = *(const bf16x8*)&sM[(mb * 16 + l16) * P2 + kb * 32 + quad * 8];
        #pragma unroll
        for (int nt = 0; nt < 2; ++nt) {
            const int nb = w * 2 + nt;
            b[nt] = *(const bf16x8*)&PWx1[((kb * 8 + nb) * 64 + lane) * 8];
        }
        #pragma unroll
        for (int mb = 0; mb < 4; ++mb)
            #pragma unroll
            for (int nt = 0; nt < 2; ++nt)
                acc3[mb][nt] = __builtin_amdgcn_mfma_f32_16x16x32_bf16(
                    a[mb], b[nt], acc3[mb][nt], 0, 0, 0);
    }
    {
        float* pRed = reinterpret_cast<float*>(eA);
        float bias[2], wx[2];
        #pragma unroll
        for (int nt = 0; nt < 2; ++nt) {
            const int col = (w * 2 + nt) * 16 + l16;
            bias[nt] = bx1[col];
            wx[nt]   = Wx2[col];
        }
        #pragma unroll
        for (int mb = 0; mb < 4; ++mb)
            #pragma unroll
            for (int r = 0; r < 4; ++r) {
                const int row = mb * 16 + quad * 4 + r;
                float p = 0.0f;
                #pragma unroll
                for (int nt = 0; nt < 2; ++nt)
                    p += silu_f(acc3[mb][nt][r] + bias[nt]) * wx[nt];
                pRed[row * PR + w * 16 + l16] = p;
            }
    }
    __syncthreads();
    if (t < 64) {
        const float* pRed = reinterpret_cast<const float*>(eA);
        float s = bx2[0];
        #pragma unroll 8
        for (int cc = 0; cc < 64; ++cc) s += pRed[t * PR + cc];
        sW[t] = tanh_f(s);
    }
    __syncthreads();

    // ---- coord atomics (1.9M total lane-ops, keep simple) ----
    if (t < 192) {
        const int e  = t / 3;
        const int d3 = t - e * 3;
        atomicAdd(&coord_agg[(size_t)sDst[e] * 3 + d3], sDiff[e][d3] * sW[e]);
    }

    // ---- msg: dst-sorted run reduction, one atomic per run per channel ----
    {
        const int ch   = t & 127;
        const int half = t >> 7;
        const int r0   = half * 32;
        float acc = 0.0f;
        #pragma unroll 4
        for (int r = 0; r < 32; ++r) {
            const int row = r0 + r;
            const int d   = sDst[row];
            acc += bf2f(sM[row * P2 + ch]);
            const bool flush = (r == 31) || (sDst[row + 1] != d);
            if (flush) {
                atomicAdd(&msg_agg[(size_t)d * HD + ch], acc);
                acc = 0.0f;
            }
        }
    }
}

// -------------------- Node kernel (16 nodes/block, grid 1250) --------------------
__global__ __launch_bounds__(256, 4) void egnn_node_kernel(
    const float* __restrict__ h, const float* __restrict__ x,
    const int* __restrict__ fixed_mask,
    const float* __restrict__ Wh1, const float* __restrict__ bh1,
    const float* __restrict__ Wh2, const float* __restrict__ bh2,
    const float* __restrict__ msg_agg, const float* __restrict__ coord_agg,
    float* __restrict__ out_h, float* __restrict__ out_x)
{
    __shared__ float sT[16][HD + 4];
    const int t  = threadIdx.x;
    const int n0 = blockIdx.x * 16;
    const int c = t & 15, ln = t >> 4;
    const int ch0 = c * 8;
    const int n  = n0 + ln;    // NN % 16 == 0, no guard needed

    if (t < 48) {
        const int l2 = t / 3, d3 = t - l2 * 3;
        const int nn = n0 + l2;
        const float add = (fixed_mask[nn] != 0) ? 0.0f : coord_agg[(size_t)nn*3 + d3];
        out_x[(size_t)nn*3 + d3] = x[(size_t)nn*3 + d3] + add;
    }

    float acc[8];
    #pragma unroll
    for (int j = 0; j < 8; ++j) acc[j] = 0.0f;

    #pragma unroll 4
    for (int kk = 0; kk < 2 * HD; ++kk) {
        const float4* wp = reinterpret_cast<const float4*>(Wh1 + (size_t)kk * HD + ch0);
        const float4 b0 = wp[0], b1 = wp[1];
        const float a = (kk < HD) ? h[(size_t)n*HD + kk]
                                  : msg_agg[(size_t)n*HD + (kk - HD)];
        acc[0] += a*b0.x; acc[1] += a*b0.y; acc[2] += a*b0.z; acc[3] += a*b0.w;
        acc[4] += a*b1.x; acc[5] += a*b1.y; acc[6] += a*b1.z; acc[7] += a*b1.w;
    }
    {
        const float4* bp = reinterpret_cast<const float4*>(bh1 + ch0);
        const float4 c0v = bp[0], c1v = bp[1];
        const float bias[8] = {c0v.x,c0v.y,c0v.z,c0v.w,c1v.x,c1v.y,c1v.z,c1v.w};
        #pragma unroll
        for (int j = 0; j < 8; ++j)
            sT[ln][ch0+j] = silu_f(acc[j] + bias[j]);
    }
    __syncthreads();

    #pragma unroll
    for (int j = 0; j < 8; ++j) acc[j] = 0.0f;
    #pragma unroll 4
    for (int kk = 0; kk < HD; ++kk) {
        const float4* wp = reinterpret_cast<const float4*>(Wh2 + (size_t)kk * HD + ch0);
        const float4 b0 = wp[0], b1 = wp[1];
        const float a = sT[ln][kk];
        acc[0] += a*b0.x; acc[1] += a*b0.y; acc[2] += a*b0.z; acc[3] += a*b0.w;
        acc[4] += a*b1.x; acc[5] += a*b1.y; acc[6] += a*b1.z; acc[7] += a*b1.w;
    }
    {
        const float4* bp = reinterpret_cast<const float4*>(bh2 + ch0);
        const float4 c0v = bp[0], c1v = bp[1];
        const float bias[8] = {c0v.x,c0v.y,c0v.z,c0v.w,c1v.x,c1v.y,c1v.z,c1v.w};
        #pragma unroll
        for (int j = 0; j < 8; ++j)
            out_h[(size_t)n*HD + ch0 + j] =
                h[(size_t)n*HD + ch0 + j] + acc[j] + bias[j];
    }
}

extern "C" void kernel_launch(void* const* d_in, const int* in_sizes, int n_in,
                              void* d_out, int out_size, void* d_ws, size_t ws_size,
                              hipStream_t stream)
{
    const float* h     = (const float*)d_in[0];
    const float* x     = (const float*)d_in[1];
    const int*   ei    = (const int*)d_in[2];
    const float* eattr = (const float*)d_in[3];
    const int*   fmask = (const int*)d_in[4];
    const float* We1   = (const float*)d_in[5];
    const float* be1   = (const float*)d_in[6];
    const float* We2   = (const float*)d_in[7];
    const float* be2   = (const float*)d_in[8];
    const float* Wx1   = (const float*)d_in[9];
    const float* bx1   = (const float*)d_in[10];
    const float* Wx2   = (const float*)d_in[11];
    const float* bx2   = (const float*)d_in[12];
    const float* Wh1   = (const float*)d_in[13];
    const float* bh1   = (const float*)d_in[14];
    const float* Wh2   = (const float*)d_in[15];
    const float* bh2   = (const float*)d_in[16];

    // workspace layout
    float* msg   = (float*)d_ws;                          // [NN,HD]
    float* coord = msg + (size_t)NN * HD;                 // [NN,3]
    int*   cnt   = (int*)(coord + (size_t)NN * 3);        // [NN] (zeroed)
    unsigned short* hb   = (unsigned short*)(cnt + NN);
    unsigned short* PWe1 = hb + (size_t)NN * HD;
    unsigned short* PWe2 = PWe1 + (size_t)(KP1/32) * 8 * 512;
    unsigned short* PWx1 = PWe2 + (size_t)4 * 8 * 512;
    int*   perm   = (int*)(PWx1 + (size_t)4 * 8 * 512);   // [NE]
    int*   cursor = perm + NE;                            // [NN]

    float* out_h = (float*)d_out;
    float* out_x = out_h + (size_t)NN * HD;

    // zero msg + coord + cnt (contiguous)
    hipMemsetAsync(d_ws, 0, (size_t)NN * (HD + 3 + 1) * sizeof(float), stream);
    egnn_prep_kernel<<<1024, 256, 0, stream>>>(h, We1, We2, Wx1, hb, PWe1, PWe2, PWx1);
    egnn_hist_kernel<<<NE / 256, 256, 0, stream>>>(ei, cnt);
    egnn_scan_kernel<<<1, 256, 0, stream>>>(cnt, cursor);
    egnn_perm_kernel<<<NE / 256, 256, 0, stream>>>(ei, cursor, perm);
    egnn_edge_kernel<<<NE / 64, 256, 0, stream>>>(
        hb, x, ei, eattr, perm, PWe1, be1, PWe2, be2, PWx1, bx1, Wx2, bx2, msg, coord);
    egnn_node_kernel<<<NN / 16, 256, 0, stream>>>(
        h, x, fmask, Wh1, bh1, Wh2, bh2, msg, coord, out_h, out_x);
}

// Round 5
// 567.142 us; speedup vs baseline: 1.2021x; 1.2021x over previous
//
#include <hip/hip_runtime.h>
#include <hip/hip_bf16.h>
#include <math.h>

#define NN   20000
#define NE   640000
#define HD   128
#define EDIM 16
#define KIN  273    // 2H + 1 + ED
#define KP1  288    // KIN padded to 9*32
#define P2   136    // t1/m LDS pitch (ushorts): 272 B, 16B-aligned rows

typedef __bf16 bf16x8 __attribute__((ext_vector_type(8)));
typedef float  f32x4  __attribute__((ext_vector_type(4)));

__device__ __forceinline__ float silu_f(float v) {
    const float e = __expf(-v);
    return v * __builtin_amdgcn_rcpf(1.0f + e);
}
__device__ __forceinline__ float tanh_f(float s) {
    const float e = __expf(2.0f * s);
    return 1.0f - 2.0f * __builtin_amdgcn_rcpf(e + 1.0f);
}
__device__ __forceinline__ unsigned short f2bf(float f) {
    __bf16 b = (__bf16)f;
    return __builtin_bit_cast(unsigned short, b);
}

// -------------------- Prep: h->bf16, pack W into MFMA B-frag order ----------
__device__ __forceinline__ void pack_one(const float* __restrict__ W, int Kreal,
                                         unsigned short* __restrict__ P, int idx) {
    const int f    = idx >> 9;
    const int r    = idx & 511;
    const int lane = r >> 3;
    const int j    = r & 7;
    const int kb   = f >> 3;
    const int nb   = f & 7;
    const int k    = kb * 32 + (lane >> 4) * 8 + j;
    const int n    = nb * 16 + (lane & 15);
    const float v  = (k < Kreal) ? W[(size_t)k * HD + n] : 0.0f;
    P[idx] = f2bf(v);
}

__global__ void egnn_prep_kernel(
    const float* __restrict__ h,
    const float* __restrict__ We1, const float* __restrict__ We2,
    const float* __restrict__ Wx1,
    unsigned short* __restrict__ hb,
    unsigned short* __restrict__ PWe1, unsigned short* __restrict__ PWe2,
    unsigned short* __restrict__ PWx1)
{
    const size_t NH = (size_t)NN * HD;
    const size_t S1 = (size_t)(KP1 / 32) * 8 * 512;
    const size_t S2 = (size_t)4 * 8 * 512;
    const size_t S3 = S2;
    const size_t total  = NH + S1 + S2 + S3;
    const size_t stride = (size_t)gridDim.x * blockDim.x;
    for (size_t i = (size_t)blockIdx.x * blockDim.x + threadIdx.x; i < total; i += stride) {
        if (i < NH) {
            hb[i] = f2bf(h[i]);
        } else if (i < NH + S1) {
            pack_one(We1, KIN, PWe1, (int)(i - NH));
        } else if (i < NH + S1 + S2) {
            pack_one(We2, HD, PWe2, (int)(i - NH - S1));
        } else {
            pack_one(Wx1, HD, PWx1, (int)(i - NH - S1 - S2));
        }
    }
}

// -------------------- Edge kernel (MFMA, 36.6KB LDS -> 4 blocks/CU) ---------
__global__ __launch_bounds__(256, 4) void egnn_edge_kernel(
    const unsigned short* __restrict__ hb, const float* __restrict__ x,
    const int* __restrict__ ei, const float* __restrict__ eattr,
    const unsigned short* __restrict__ PWe1, const float* __restrict__ be1,
    const unsigned short* __restrict__ PWe2, const float* __restrict__ be2,
    const unsigned short* __restrict__ PWx1, const float* __restrict__ bx1,
    const float* __restrict__ Wx2, const float* __restrict__ bx2,
    float* __restrict__ msg_agg, float* __restrict__ coord_agg)
{
    __shared__ __align__(16) unsigned short sT[64 * P2];   // 17408 B; tail of life: GEMM2 reads. Reused as fp32 red[4][64].
    __shared__ __align__(16) unsigned short sM[64 * P2];   // 17408 B; first 4KB aliased as tail chunk during GEMM1.
    __shared__ int   sSrc[64], sDst[64];
    __shared__ float sDiff[64][3];
    __shared__ float sW[64];

    const int t  = threadIdx.x;
    const int e0 = blockIdx.x * 64;

    // tail buffer [64 rows][32 cols] bf16, aliased onto sM's first 4096 B
    unsigned short* tail = sM;

    if (t < 64) {
        const int e = e0 + t;
        const int s = ei[e];
        const int d = ei[NE + e];
        sSrc[t] = s; sDst[t] = d;
        const float dx = x[s*3+0] - x[d*3+0];
        const float dy = x[s*3+1] - x[d*3+1];
        const float dz = x[s*3+2] - x[d*3+2];
        sDiff[t][0] = dx; sDiff[t][1] = dy; sDiff[t][2] = dz;
        // dist goes into tail col 0
        tail[t * 32 + 0] = f2bf((dx*dx + dy*dy + dz*dz) * 0.01f);
    }
    // tail cols 1..16 = eattr, 17..31 = 0 (cols built by 256 threads: 4 per edge x 8)
    {
        const int eL = t >> 2, q = t & 3;
        #pragma unroll
        for (int jj = 0; jj < 8; ++jj) {
            const int col = q * 8 + jj;
            if (col == 0) continue;                    // dist written above
            float v = 0.0f;
            if (col <= EDIM) v = eattr[(size_t)(e0 + eL) * EDIM + (col - 1)];
            tail[eL * 32 + col] = f2bf(v);
        }
    }
    __syncthreads();

    const int lane = t & 63;
    const int w    = t >> 6;
    const int quad = lane >> 4;
    const int l16  = lane & 15;

    // per-lane byte offsets into hb for this lane's 4 A-rows (src & dst halves)
    int soff[4], doff[4];
    #pragma unroll
    for (int mb = 0; mb < 4; ++mb) {
        const int row = mb * 16 + l16;
        soff[mb] = sSrc[row] * (HD * 2) + quad * 16;   // bytes
        doff[mb] = sDst[row] * (HD * 2) + quad * 16;
    }
    const char* hbb = (const char*)hb;

    // ---- GEMM1: e_in[64,288] @ We1; A direct from global, tail from LDS ----
    f32x4 acc1[4][2];
    #pragma unroll
    for (int mb = 0; mb < 4; ++mb)
        #pragma unroll
        for (int nt = 0; nt < 2; ++nt) acc1[mb][nt] = (f32x4){0.f,0.f,0.f,0.f};

    #pragma unroll
    for (int kb = 0; kb < 9; ++kb) {
        bf16x8 a[4], b[2];
        if (kb < 4) {
            #pragma unroll
            for (int mb = 0; mb < 4; ++mb)
                a[mb] = *(const bf16x8*)(hbb + soff[mb] + kb * 64);
        } else if (kb < 8) {
            #pragma unroll
            for (int mb = 0; mb < 4; ++mb)
                a[mb] = *(const bf16x8*)(hbb + doff[mb] + (kb - 4) * 64);
        } else {
            #pragma unroll
            for (int mb = 0; mb < 4; ++mb)
                a[mb] = *(const bf16x8*)&tail[(mb * 16 + l16) * 32 + quad * 8];
        }
        #pragma unroll
        for (int nt = 0; nt < 2; ++nt) {
            const int nb = w * 2 + nt;
            b[nt] = *(const bf16x8*)&PWe1[((kb * 8 + nb) * 64 + lane) * 8];
        }
        #pragma unroll
        for (int mb = 0; mb < 4; ++mb)
            #pragma unroll
            for (int nt = 0; nt < 2; ++nt)
                acc1[mb][nt] = __builtin_amdgcn_mfma_f32_16x16x32_bf16(
                    a[mb], b[nt], acc1[mb][nt], 0, 0, 0);
    }
    // t1 = silu(acc1 + be1) -> sT
    #pragma unroll
    for (int nt = 0; nt < 2; ++nt) {
        const int col = (w * 2 + nt) * 16 + l16;
        const float bias = be1[col];
        #pragma unroll
        for (int mb = 0; mb < 4; ++mb)
            #pragma unroll
            for (int r = 0; r < 4; ++r) {
                const int row = mb * 16 + quad * 4 + r;
                sT[row * P2 + col] = f2bf(silu_f(acc1[mb][nt][r] + bias));
            }
    }
    __syncthreads();   // sT complete; also: all tail reads done -> sM writable

    // ---- GEMM2: t1 @ We2 -> m_ij ----
    f32x4 acc2[4][2];
    #pragma unroll
    for (int mb = 0; mb < 4; ++mb)
        #pragma unroll
        for (int nt = 0; nt < 2; ++nt) acc2[mb][nt] = (f32x4){0.f,0.f,0.f,0.f};
    #pragma unroll
    for (int kb = 0; kb < 4; ++kb) {
        bf16x8 a[4], b[2];
        #pragma unroll
        for (int mb = 0; mb < 4; ++mb)
            a[mb] = *(const bf16x8*)&sT[(mb * 16 + l16) * P2 + kb * 32 + quad * 8];
        #pragma unroll
        for (int nt = 0; nt < 2; ++nt) {
            const int nb = w * 2 + nt;
            b[nt] = *(const bf16x8*)&PWe2[((kb * 8 + nb) * 64 + lane) * 8];
        }
        #pragma unroll
        for (int mb = 0; mb < 4; ++mb)
            #pragma unroll
            for (int nt = 0; nt < 2; ++nt)
                acc2[mb][nt] = __builtin_amdgcn_mfma_f32_16x16x32_bf16(
                    a[mb], b[nt], acc2[mb][nt], 0, 0, 0);
    }
    // m_ij = silu(acc2 + be2): write sM AND issue msg atomics from registers
    #pragma unroll
    for (int nt = 0; nt < 2; ++nt) {
        const int col = (w * 2 + nt) * 16 + l16;
        const float bias = be2[col];
        #pragma unroll
        for (int mb = 0; mb < 4; ++mb)
            #pragma unroll
            for (int r = 0; r < 4; ++r) {
                const int row = mb * 16 + quad * 4 + r;
                const float s = silu_f(acc2[mb][nt][r] + bias);
                sM[row * P2 + col] = f2bf(s);
                atomicAdd(&msg_agg[(size_t)sDst[row] * HD + col], s);
            }
    }
    __syncthreads();   // sM complete; also: all sT reads done -> red writable

    // ---- GEMM3: m_ij @ Wx1 ----
    f32x4 acc3[4][2];
    #pragma unroll
    for (int mb = 0; mb < 4; ++mb)
        #pragma unroll
        for (int nt = 0; nt < 2; ++nt) acc3[mb][nt] = (f32x4){0.f,0.f,0.f,0.f};
    #pragma unroll
    for (int kb = 0; kb < 4; ++kb) {
        bf16x8 a[4], b[2];
        #pragma unroll
        for (int mb = 0; mb < 4; ++mb)
            a[mb] = *(const bf16x8*)&sM[(mb * 16 + l16) * P2 + kb * 32 + quad * 8];
        #pragma unroll
        for (int nt = 0; nt < 2; ++nt) {
            const int nb = w * 2 + nt;
            b[nt] = *(const bf16x8*)&PWx1[((kb * 8 + nb) * 64 + lane) * 8];
        }
        #pragma unroll
        for (int mb = 0; mb < 4; ++mb)
            #pragma unroll
            for (int nt = 0; nt < 2; ++nt)
                acc3[mb][nt] = __builtin_amdgcn_mfma_f32_16x16x32_bf16(
                    a[mb], b[nt], acc3[mb][nt], 0, 0, 0);
    }
    // coord_w: per-(mb,r) partial over this thread's 2 cols, then shfl-reduce
    {
        float bias[2], wx[2];
        #pragma unroll
        for (int nt = 0; nt < 2; ++nt) {
            const int col = (w * 2 + nt) * 16 + l16;
            bias[nt] = bx1[col];
            wx[nt]   = Wx2[col];
        }
        float p[4][4];
        #pragma unroll
        for (int mb = 0; mb < 4; ++mb)
            #pragma unroll
            for (int r = 0; r < 4; ++r) {
                float v = 0.0f;
                #pragma unroll
                for (int nt = 0; nt < 2; ++nt)
                    v += silu_f(acc3[mb][nt][r] + bias[nt]) * wx[nt];
                p[mb][r] = v;
            }
        // butterfly over l16 (offsets 1,2,4,8 stay within the 16-lane group)
        #pragma unroll
        for (int off = 8; off >= 1; off >>= 1)
            #pragma unroll
            for (int mb = 0; mb < 4; ++mb)
                #pragma unroll
                for (int r = 0; r < 4; ++r)
                    p[mb][r] += __shfl_xor(p[mb][r], off, 64);
        if (l16 == 0) {
            float* red = reinterpret_cast<float*>(sT);   // [4][64]
            #pragma unroll
            for (int mb = 0; mb < 4; ++mb)
                #pragma unroll
                for (int r = 0; r < 4; ++r)
                    red[w * 64 + mb * 16 + quad * 4 + r] = p[mb][r];
        }
    }
    __syncthreads();
    if (t < 64) {
        const float* red = reinterpret_cast<const float*>(sT);
        sW[t] = tanh_f(red[t] + red[64 + t] + red[128 + t] + red[192 + t] + bx2[0]);
    }
    __syncthreads();

    if (t < 192) {
        const int e  = t / 3;
        const int d3 = t - e * 3;
        atomicAdd(&coord_agg[(size_t)sDst[e] * 3 + d3], sDiff[e][d3] * sW[e]);
    }
}

// -------------------- Node kernel (16 nodes/block, grid 1250) --------------------
__global__ __launch_bounds__(256, 4) void egnn_node_kernel(
    const float* __restrict__ h, const float* __restrict__ x,
    const int* __restrict__ fixed_mask,
    const float* __restrict__ Wh1, const float* __restrict__ bh1,
    const float* __restrict__ Wh2, const float* __restrict__ bh2,
    const float* __restrict__ msg_agg, const float* __restrict__ coord_agg,
    float* __restrict__ out_h, float* __restrict__ out_x)
{
    __shared__ float sT[16][HD + 4];
    const int t  = threadIdx.x;
    const int n0 = blockIdx.x * 16;
    const int c = t & 15, ln = t >> 4;
    const int ch0 = c * 8;
    const int n  = n0 + ln;

    if (t < 48) {
        const int l2 = t / 3, d3 = t - l2 * 3;
        const int nn = n0 + l2;
        const float add = (fixed_mask[nn] != 0) ? 0.0f : coord_agg[(size_t)nn*3 + d3];
        out_x[(size_t)nn*3 + d3] = x[(size_t)nn*3 + d3] + add;
    }

    float acc[8];
    #pragma unroll
    for (int j = 0; j < 8; ++j) acc[j] = 0.0f;

    #pragma unroll 4
    for (int kk = 0; kk < 2 * HD; ++kk) {
        const float4* wp = reinterpret_cast<const float4*>(Wh1 + (size_t)kk * HD + ch0);
        const float4 b0 = wp[0], b1 = wp[1];
        const float a = (kk < HD) ? h[(size_t)n*HD + kk]
                                  : msg_agg[(size_t)n*HD + (kk - HD)];
        acc[0] += a*b0.x; acc[1] += a*b0.y; acc[2] += a*b0.z; acc[3] += a*b0.w;
        acc[4] += a*b1.x; acc[5] += a*b1.y; acc[6] += a*b1.z; acc[7] += a*b1.w;
    }
    {
        const float4* bp = reinterpret_cast<const float4*>(bh1 + ch0);
        const float4 c0v = bp[0], c1v = bp[1];
        const float bias[8] = {c0v.x,c0v.y,c0v.z,c0v.w,c1v.x,c1v.y,c1v.z,c1v.w};
        #pragma unroll
        for (int j = 0; j < 8; ++j)
            sT[ln][ch0+j] = silu_f(acc[j] + bias[j]);
    }
    __syncthreads();

    #pragma unroll
    for (int j = 0; j < 8; ++j) acc[j] = 0.0f;
    #pragma unroll 4
    for (int kk = 0; kk < HD; ++kk) {
        const float4* wp = reinterpret_cast<const float4*>(Wh2 + (size_t)kk * HD + ch0);
        const float4 b0 = wp[0], b1 = wp[1];
        const float a = sT[ln][kk];
        acc[0] += a*b0.x; acc[1] += a*b0.y; acc[2] += a*b0.z; acc[3] += a*b0.w;
        acc[4] += a*b1.x; acc[5] += a*b1.y; acc[6] += a*b1.z; acc[7] += a*b1.w;
    }
    {
        const float4* bp = reinterpret_cast<const float4*>(bh2 + ch0);
        const float4 c0v = bp[0], c1v = bp[1];
        const float bias[8] = {c0v.x,c0v.y,c0v.z,c0v.w,c1v.x,c1v.y,c1v.z,c1v.w};
        #pragma unroll
        for (int j = 0; j < 8; ++j)
            out_h[(size_t)n*HD + ch0 + j] =
                h[(size_t)n*HD + ch0 + j] + acc[j] + bias[j];
    }
}

extern "C" void kernel_launch(void* const* d_in, const int* in_sizes, int n_in,
                              void* d_out, int out_size, void* d_ws, size_t ws_size,
                              hipStream_t stream)
{
    const float* h     = (const float*)d_in[0];
    const float* x     = (const float*)d_in[1];
    const int*   ei    = (const int*)d_in[2];
    const float* eattr = (const float*)d_in[3];
    const int*   fmask = (const int*)d_in[4];
    const float* We1   = (const float*)d_in[5];
    const float* be1   = (const float*)d_in[6];
    const float* We2   = (const float*)d_in[7];
    const float* be2   = (const float*)d_in[8];
    const float* Wx1   = (const float*)d_in[9];
    const float* bx1   = (const float*)d_in[10];
    const float* Wx2   = (const float*)d_in[11];
    const float* bx2   = (const float*)d_in[12];
    const float* Wh1   = (const float*)d_in[13];
    const float* bh1   = (const float*)d_in[14];
    const float* Wh2   = (const float*)d_in[15];
    const float* bh2   = (const float*)d_in[16];

    float* msg   = (float*)d_ws;                          // [NN,HD]
    float* coord = msg + (size_t)NN * HD;                 // [NN,3]
    unsigned short* hb   = (unsigned short*)(coord + (size_t)NN * 3);
    unsigned short* PWe1 = hb + (size_t)NN * HD;
    unsigned short* PWe2 = PWe1 + (size_t)(KP1/32) * 8 * 512;
    unsigned short* PWx1 = PWe2 + (size_t)4 * 8 * 512;

    float* out_h = (float*)d_out;
    float* out_x = out_h + (size_t)NN * HD;

    hipMemsetAsync(d_ws, 0, (size_t)NN * (HD + 3) * sizeof(float), stream);
    egnn_prep_kernel<<<1024, 256, 0, stream>>>(h, We1, We2, Wx1, hb, PWe1, PWe2, PWx1);
    egnn_edge_kernel<<<NE / 64, 256, 0, stream>>>(
        hb, x, ei, eattr, PWe1, be1, PWe2, be2, PWx1, bx1, Wx2, bx2, msg, coord);
    egnn_node_kernel<<<NN / 16, 256, 0, stream>>>(
        h, x, fmask, Wh1, bh1, Wh2, bh2, msg, coord, out_h, out_x);
}

// Round 6
// 542.031 us; speedup vs baseline: 1.2577x; 1.0463x over previous
//
#include <hip/hip_runtime.h>
#include <hip/hip_bf16.h>
#include <math.h>

#define NN   20000
#define NE   640000
#define HD   128
#define EDIM 16
#define KIN  273    // 2H + 1 + ED
#define KP1  288    // KIN padded to 9*32
#define P2   136    // LDS pitch (ushorts): 272 B, 16B-aligned rows

typedef __bf16 bf16x8 __attribute__((ext_vector_type(8)));
typedef float  f32x4  __attribute__((ext_vector_type(4)));

__device__ __forceinline__ float silu_f(float v) {
    const float e = __expf(-v);
    return v * __builtin_amdgcn_rcpf(1.0f + e);
}
__device__ __forceinline__ float tanh_f(float s) {
    const float e = __expf(2.0f * s);
    return 1.0f - 2.0f * __builtin_amdgcn_rcpf(e + 1.0f);
}
__device__ __forceinline__ unsigned short f2bf(float f) {
    __bf16 b = (__bf16)f;
    return __builtin_bit_cast(unsigned short, b);
}
__device__ __forceinline__ float bf2f(unsigned short u) {
    __bf16 b = __builtin_bit_cast(__bf16, u);
    return (float)b;
}

// -------------------- Prep: h->bf16, pack W into MFMA B-frag order ----------
// frag (kb,nb): elem[lane*8+j] = W[kb*32+(lane>>4)*8+j][nb*16+(lane&15)]
__device__ __forceinline__ void pack_one(const float* __restrict__ W, int Kreal,
                                         unsigned short* __restrict__ P, int idx) {
    const int f    = idx >> 9;
    const int r    = idx & 511;
    const int lane = r >> 3;
    const int j    = r & 7;
    const int kb   = f >> 3;
    const int nb   = f & 7;
    const int k    = kb * 32 + (lane >> 4) * 8 + j;
    const int n    = nb * 16 + (lane & 15);
    const float v  = (k < Kreal) ? W[(size_t)k * HD + n] : 0.0f;
    P[idx] = f2bf(v);
}

#define S_WE1 36864   // 9 kb x 8 nb x 512
#define S_W4  16384   // 4 kb x 8 nb x 512
#define S_WH1 32768   // 8 kb x 8 nb x 512

__global__ void egnn_prep_kernel(
    const float* __restrict__ h,
    const float* __restrict__ We1, const float* __restrict__ We2,
    const float* __restrict__ Wx1, const float* __restrict__ Wh1,
    const float* __restrict__ Wh2,
    unsigned short* __restrict__ hb,
    unsigned short* __restrict__ PWe1, unsigned short* __restrict__ PWe2,
    unsigned short* __restrict__ PWx1, unsigned short* __restrict__ PWh1,
    unsigned short* __restrict__ PWh2)
{
    const size_t NH = (size_t)NN * HD;
    const size_t total  = NH + S_WE1 + 3 * S_W4 + S_WH1;
    const size_t stride = (size_t)gridDim.x * blockDim.x;
    for (size_t i = (size_t)blockIdx.x * blockDim.x + threadIdx.x; i < total; i += stride) {
        if (i < NH) { hb[i] = f2bf(h[i]); continue; }
        size_t r = i - NH;
        if (r < S_WE1) { pack_one(We1, KIN, PWe1, (int)r); continue; }
        r -= S_WE1;
        if (r < S_W4) { pack_one(We2, HD, PWe2, (int)r); continue; }
        r -= S_W4;
        if (r < S_W4) { pack_one(Wx1, HD, PWx1, (int)r); continue; }
        r -= S_W4;
        if (r < S_WH1) { pack_one(Wh1, 2 * HD, PWh1, (int)r); continue; }
        r -= S_WH1;
        pack_one(Wh2, HD, PWh2, (int)r);
    }
}

// -------------------- CSR build (counting sort by dst) --------------------
__global__ void egnn_hist_kernel(const int* __restrict__ ei, int* __restrict__ cnt) {
    const int e = blockIdx.x * 256 + threadIdx.x;   // grid exactly NE/256
    atomicAdd(&cnt[ei[NE + e]], 1);
}

// one block, 1024 threads, SEG=20: exclusive prefix sum cnt -> cursor
__global__ void egnn_scan_kernel(const int* __restrict__ cnt, int* __restrict__ cursor) {
    __shared__ int ls[1024];
    const int t = threadIdx.x;
    const int base = t * 20;
    int c[20];
    int s = 0;
    #pragma unroll
    for (int i = 0; i < 20; ++i) {
        const int idx = base + i;
        c[i] = (idx < NN) ? cnt[idx] : 0;
        s += c[i];
    }
    ls[t] = s;
    __syncthreads();
    int v = s;
    for (int off = 1; off < 1024; off <<= 1) {
        const int u = (t >= off) ? ls[t - off] : 0;
        __syncthreads();
        v += u;
        ls[t] = v;
        __syncthreads();
    }
    int run = v - s;
    #pragma unroll
    for (int i = 0; i < 20; ++i) {
        const int idx = base + i;
        if (idx < NN) { cursor[idx] = run; run += c[i]; }
    }
}

__global__ void egnn_perm_kernel(const int* __restrict__ ei,
                                 int* __restrict__ cursor, int* __restrict__ perm) {
    const int e = blockIdx.x * 256 + threadIdx.x;
    const int pos = atomicAdd(&cursor[ei[NE + e]], 1);
    perm[pos] = e;
}

// -------------------- Edge kernel (MFMA, dst-sorted, 4 blocks/CU) ---------
__global__ __launch_bounds__(256, 4) void egnn_edge_kernel(
    const unsigned short* __restrict__ hb, const float* __restrict__ x,
    const int* __restrict__ ei, const float* __restrict__ eattr,
    const int* __restrict__ perm,
    const unsigned short* __restrict__ PWe1, const float* __restrict__ be1,
    const unsigned short* __restrict__ PWe2, const float* __restrict__ be2,
    const unsigned short* __restrict__ PWx1, const float* __restrict__ bx1,
    const float* __restrict__ Wx2, const float* __restrict__ bx2,
    float* __restrict__ msg_agg, float* __restrict__ coord_agg)
{
    __shared__ __align__(16) unsigned short sT[64 * P2];  // t1; reused as fp32 red[4][64]
    __shared__ __align__(16) unsigned short sM[64 * P2];  // m_ij; first 4KB = tail during GEMM1
    __shared__ int   sE[64], sSrc[64], sDst[64];
    __shared__ float sDiff[64][3];
    __shared__ float sW[64];

    const int t  = threadIdx.x;
    const int e0 = blockIdx.x * 64;
    unsigned short* tail = sM;   // [64][32] bf16

    if (t < 64) {
        const int e = perm[e0 + t];
        sE[t] = e;
        const int s = ei[e];
        const int d = ei[NE + e];
        sSrc[t] = s; sDst[t] = d;
        const float dx = x[s*3+0] - x[d*3+0];
        const float dy = x[s*3+1] - x[d*3+1];
        const float dz = x[s*3+2] - x[d*3+2];
        sDiff[t][0] = dx; sDiff[t][1] = dy; sDiff[t][2] = dz;
        tail[t * 32 + 0] = f2bf((dx*dx + dy*dy + dz*dz) * 0.01f);
    }
    __syncthreads();   // sE valid before tail build gathers eattr
    {
        const int eL = t >> 2, q = t & 3;
        const int eG = sE[eL];
        #pragma unroll
        for (int jj = 0; jj < 8; ++jj) {
            const int col = q * 8 + jj;
            if (col == 0) continue;
            float v = 0.0f;
            if (col <= EDIM) v = eattr[(size_t)eG * EDIM + (col - 1)];
            tail[eL * 32 + col] = f2bf(v);
        }
    }
    __syncthreads();

    const int lane = t & 63;
    const int w    = t >> 6;
    const int quad = lane >> 4;
    const int l16  = lane & 15;

    int soff[4], doff[4];
    #pragma unroll
    for (int mb = 0; mb < 4; ++mb) {
        const int row = mb * 16 + l16;
        soff[mb] = sSrc[row] * (HD * 2) + quad * 16;
        doff[mb] = sDst[row] * (HD * 2) + quad * 16;
    }
    const char* hbb = (const char*)hb;

    // ---- GEMM1: e_in[64,288] @ We1 ----
    f32x4 acc1[4][2];
    #pragma unroll
    for (int mb = 0; mb < 4; ++mb)
        #pragma unroll
        for (int nt = 0; nt < 2; ++nt) acc1[mb][nt] = (f32x4){0.f,0.f,0.f,0.f};

    #pragma unroll
    for (int kb = 0; kb < 9; ++kb) {
        bf16x8 a[4], b[2];
        if (kb < 4) {
            #pragma unroll
            for (int mb = 0; mb < 4; ++mb)
                a[mb] = *(const bf16x8*)(hbb + soff[mb] + kb * 64);
        } else if (kb < 8) {
            #pragma unroll
            for (int mb = 0; mb < 4; ++mb)
                a[mb] = *(const bf16x8*)(hbb + doff[mb] + (kb - 4) * 64);
        } else {
            #pragma unroll
            for (int mb = 0; mb < 4; ++mb)
                a[mb] = *(const bf16x8*)&tail[(mb * 16 + l16) * 32 + quad * 8];
        }
        #pragma unroll
        for (int nt = 0; nt < 2; ++nt) {
            const int nb = w * 2 + nt;
            b[nt] = *(const bf16x8*)&PWe1[((kb * 8 + nb) * 64 + lane) * 8];
        }
        #pragma unroll
        for (int mb = 0; mb < 4; ++mb)
            #pragma unroll
            for (int nt = 0; nt < 2; ++nt)
                acc1[mb][nt] = __builtin_amdgcn_mfma_f32_16x16x32_bf16(
                    a[mb], b[nt], acc1[mb][nt], 0, 0, 0);
    }
    #pragma unroll
    for (int nt = 0; nt < 2; ++nt) {
        const int col = (w * 2 + nt) * 16 + l16;
        const float bias = be1[col];
        #pragma unroll
        for (int mb = 0; mb < 4; ++mb)
            #pragma unroll
            for (int r = 0; r < 4; ++r) {
                const int row = mb * 16 + quad * 4 + r;
                sT[row * P2 + col] = f2bf(silu_f(acc1[mb][nt][r] + bias));
            }
    }
    __syncthreads();   // sT done; tail reads done -> sM writable

    // ---- GEMM2: t1 @ We2 -> m_ij ----
    f32x4 acc2[4][2];
    #pragma unroll
    for (int mb = 0; mb < 4; ++mb)
        #pragma unroll
        for (int nt = 0; nt < 2; ++nt) acc2[mb][nt] = (f32x4){0.f,0.f,0.f,0.f};
    #pragma unroll
    for (int kb = 0; kb < 4; ++kb) {
        bf16x8 a[4], b[2];
        #pragma unroll
        for (int mb = 0; mb < 4; ++mb)
            a[mb] = *(const bf16x8*)&sT[(mb * 16 + l16) * P2 + kb * 32 + quad * 8];
        #pragma unroll
        for (int nt = 0; nt < 2; ++nt) {
            const int nb = w * 2 + nt;
            b[nt] = *(const bf16x8*)&PWe2[((kb * 8 + nb) * 64 + lane) * 8];
        }
        #pragma unroll
        for (int mb = 0; mb < 4; ++mb)
            #pragma unroll
            for (int nt = 0; nt < 2; ++nt)
                acc2[mb][nt] = __builtin_amdgcn_mfma_f32_16x16x32_bf16(
                    a[mb], b[nt], acc2[mb][nt], 0, 0, 0);
    }
    #pragma unroll
    for (int nt = 0; nt < 2; ++nt) {
        const int col = (w * 2 + nt) * 16 + l16;
        const float bias = be2[col];
        #pragma unroll
        for (int mb = 0; mb < 4; ++mb)
            #pragma unroll
            for (int r = 0; r < 4; ++r) {
                const int row = mb * 16 + quad * 4 + r;
                sM[row * P2 + col] = f2bf(silu_f(acc2[mb][nt][r] + bias));
            }
    }
    __syncthreads();   // sM done; sT reads done -> red writable

    // ---- msg: dst-sorted run reduction (sorted => ~2-3 runs/block) ----
    {
        const int ch   = t & 127;
        const int half = t >> 7;
        const int r0   = half * 32;
        float acc = 0.0f;
        #pragma unroll 4
        for (int r = 0; r < 32; ++r) {
            const int row = r0 + r;
            const int d   = sDst[row];
            acc += bf2f(sM[row * P2 + ch]);
            const bool flush = (r == 31) || (sDst[row + 1] != d);
            if (flush) {
                atomicAdd(&msg_agg[(size_t)d * HD + ch], acc);
                acc = 0.0f;
            }
        }
    }

    // ---- GEMM3: m_ij @ Wx1 -> coord_w ----
    f32x4 acc3[4][2];
    #pragma unroll
    for (int mb = 0; mb < 4; ++mb)
        #pragma unroll
        for (int nt = 0; nt < 2; ++nt) acc3[mb][nt] = (f32x4){0.f,0.f,0.f,0.f};
    #pragma unroll
    for (int kb = 0; kb < 4; ++kb) {
        bf16x8 a[4], b[2];
        #pragma unroll
        for (int mb = 0; mb < 4; ++mb)
            a[mb] = *(const bf16x8*)&sM[(mb * 16 + l16) * P2 + kb * 32 + quad * 8];
        #pragma unroll
        for (int nt = 0; nt < 2; ++nt) {
            const int nb = w * 2 + nt;
            b[nt] = *(const bf16x8*)&PWx1[((kb * 8 + nb) * 64 + lane) * 8];
        }
        #pragma unroll
        for (int mb = 0; mb < 4; ++mb)
            #pragma unroll
            for (int nt = 0; nt < 2; ++nt)
                acc3[mb][nt] = __builtin_amdgcn_mfma_f32_16x16x32_bf16(
                    a[mb], b[nt], acc3[mb][nt], 0, 0, 0);
    }
    {
        float bias[2], wx[2];
        #pragma unroll
        for (int nt = 0; nt < 2; ++nt) {
            const int col = (w * 2 + nt) * 16 + l16;
            bias[nt] = bx1[col];
            wx[nt]   = Wx2[col];
        }
        float p[4][4];
        #pragma unroll
        for (int mb = 0; mb < 4; ++mb)
            #pragma unroll
            for (int r = 0; r < 4; ++r) {
                float v = 0.0f;
                #pragma unroll
                for (int nt = 0; nt < 2; ++nt)
                    v += silu_f(acc3[mb][nt][r] + bias[nt]) * wx[nt];
                p[mb][r] = v;
            }
        #pragma unroll
        for (int off = 8; off >= 1; off >>= 1)
            #pragma unroll
            for (int mb = 0; mb < 4; ++mb)
                #pragma unroll
                for (int r = 0; r < 4; ++r)
                    p[mb][r] += __shfl_xor(p[mb][r], off, 64);
        if (l16 == 0) {
            float* red = reinterpret_cast<float*>(sT);
            #pragma unroll
            for (int mb = 0; mb < 4; ++mb)
                #pragma unroll
                for (int r = 0; r < 4; ++r)
                    red[w * 64 + mb * 16 + quad * 4 + r] = p[mb][r];
        }
    }
    __syncthreads();
    if (t < 64) {
        const float* red = reinterpret_cast<const float*>(sT);
        sW[t] = tanh_f(red[t] + red[64 + t] + red[128 + t] + red[192 + t] + bx2[0]);
    }
    __syncthreads();

    if (t < 192) {
        const int e  = t / 3;
        const int d3 = t - e * 3;
        atomicAdd(&coord_agg[(size_t)sDst[e] * 3 + d3], sDiff[e][d3] * sW[e]);
    }
}

// -------------------- Node kernel (MFMA, 64 nodes/block) --------------------
__global__ __launch_bounds__(256, 4) void egnn_node_kernel(
    const unsigned short* __restrict__ hb, const float* __restrict__ h,
    const float* __restrict__ x, const int* __restrict__ fixed_mask,
    const unsigned short* __restrict__ PWh1, const float* __restrict__ bh1,
    const unsigned short* __restrict__ PWh2, const float* __restrict__ bh2,
    const float* __restrict__ msg_agg, const float* __restrict__ coord_agg,
    float* __restrict__ out_h, float* __restrict__ out_x)
{
    __shared__ __align__(16) unsigned short sTn[64 * P2];
    const int t  = threadIdx.x;
    const int n0 = blockIdx.x * 64;
    const int lane = t & 63;
    const int w    = t >> 6;
    const int quad = lane >> 4;
    const int l16  = lane & 15;

    if (t < 192) {
        const int ln = t / 3, d3 = t - ln * 3;
        const int n  = n0 + ln;
        if (n < NN) {
            const float add = (fixed_mask[n] != 0) ? 0.0f : coord_agg[(size_t)n*3 + d3];
            out_x[(size_t)n*3 + d3] = x[(size_t)n*3 + d3] + add;
        }
    }

    int nrow[4];
    #pragma unroll
    for (int mb = 0; mb < 4; ++mb) nrow[mb] = min(n0 + mb * 16 + l16, NN - 1);

    // ---- GEMM1: [h||msg][64,256] @ Wh1 ----
    f32x4 acc[4][2];
    #pragma unroll
    for (int mb = 0; mb < 4; ++mb)
        #pragma unroll
        for (int nt = 0; nt < 2; ++nt) acc[mb][nt] = (f32x4){0.f,0.f,0.f,0.f};

    #pragma unroll
    for (int kb = 0; kb < 8; ++kb) {
        bf16x8 a[4], b[2];
        if (kb < 4) {
            #pragma unroll
            for (int mb = 0; mb < 4; ++mb)
                a[mb] = *(const bf16x8*)&hb[(size_t)nrow[mb] * HD + kb * 32 + quad * 8];
        } else {
            #pragma unroll
            for (int mb = 0; mb < 4; ++mb) {
                const float* mp = msg_agg + (size_t)nrow[mb] * HD + (kb - 4) * 32 + quad * 8;
                const float4 v0 = ((const float4*)mp)[0];
                const float4 v1 = ((const float4*)mp)[1];
                bf16x8 av;
                av[0]=(__bf16)v0.x; av[1]=(__bf16)v0.y; av[2]=(__bf16)v0.z; av[3]=(__bf16)v0.w;
                av[4]=(__bf16)v1.x; av[5]=(__bf16)v1.y; av[6]=(__bf16)v1.z; av[7]=(__bf16)v1.w;
                a[mb] = av;
            }
        }
        #pragma unroll
        for (int nt = 0; nt < 2; ++nt) {
            const int nb = w * 2 + nt;
            b[nt] = *(const bf16x8*)&PWh1[((kb * 8 + nb) * 64 + lane) * 8];
        }
        #pragma unroll
        for (int mb = 0; mb < 4; ++mb)
            #pragma unroll
            for (int nt = 0; nt < 2; ++nt)
                acc[mb][nt] = __builtin_amdgcn_mfma_f32_16x16x32_bf16(
                    a[mb], b[nt], acc[mb][nt], 0, 0, 0);
    }
    #pragma unroll
    for (int nt = 0; nt < 2; ++nt) {
        const int col = (w * 2 + nt) * 16 + l16;
        const float bias = bh1[col];
        #pragma unroll
        for (int mb = 0; mb < 4; ++mb)
            #pragma unroll
            for (int r = 0; r < 4; ++r) {
                const int row = mb * 16 + quad * 4 + r;
                sTn[row * P2 + col] = f2bf(silu_f(acc[mb][nt][r] + bias));
            }
    }
    __syncthreads();

    // ---- GEMM2: sTn @ Wh2, out_h = h + acc + bh2 ----
    #pragma unroll
    for (int mb = 0; mb < 4; ++mb)
        #pragma unroll
        for (int nt = 0; nt < 2; ++nt) acc[mb][nt] = (f32x4){0.f,0.f,0.f,0.f};
    #pragma unroll
    for (int kb = 0; kb < 4; ++kb) {
        bf16x8 a[4], b[2];
        #pragma unroll
        for (int mb = 0; mb < 4; ++mb)
            a[mb] = *(const bf16x8*)&sTn[(mb * 16 + l16) * P2 + kb * 32 + quad * 8];
        #pragma unroll
        for (int nt = 0; nt < 2; ++nt) {
            const int nb = w * 2 + nt;
            b[nt] = *(const bf16x8*)&PWh2[((kb * 8 + nb) * 64 + lane) * 8];
        }
        #pragma unroll
        for (int mb = 0; mb < 4; ++mb)
            #pragma unroll
            for (int nt = 0; nt < 2; ++nt)
                acc[mb][nt] = __builtin_amdgcn_mfma_f32_16x16x32_bf16(
                    a[mb], b[nt], acc[mb][nt], 0, 0, 0);
    }
    #pragma unroll
    for (int nt = 0; nt < 2; ++nt) {
        const int col = (w * 2 + nt) * 16 + l16;
        const float bias = bh2[col];
        #pragma unroll
        for (int mb = 0; mb < 4; ++mb)
            #pragma unroll
            for (int r = 0; r < 4; ++r) {
                const int row = mb * 16 + quad * 4 + r;
                const int n   = n0 + row;
                if (n < NN)
                    out_h[(size_t)n * HD + col] =
                        h[(size_t)n * HD + col] + acc[mb][nt][r] + bias;
            }
    }
}

extern "C" void kernel_launch(void* const* d_in, const int* in_sizes, int n_in,
                              void* d_out, int out_size, void* d_ws, size_t ws_size,
                              hipStream_t stream)
{
    const float* h     = (const float*)d_in[0];
    const float* x     = (const float*)d_in[1];
    const int*   ei    = (const int*)d_in[2];
    const float* eattr = (const float*)d_in[3];
    const int*   fmask = (const int*)d_in[4];
    const float* We1   = (const float*)d_in[5];
    const float* be1   = (const float*)d_in[6];
    const float* We2   = (const float*)d_in[7];
    const float* be2   = (const float*)d_in[8];
    const float* Wx1   = (const float*)d_in[9];
    const float* bx1   = (const float*)d_in[10];
    const float* Wx2   = (const float*)d_in[11];
    const float* bx2   = (const float*)d_in[12];
    const float* Wh1   = (const float*)d_in[13];
    const float* bh1   = (const float*)d_in[14];
    const float* Wh2   = (const float*)d_in[15];
    const float* bh2   = (const float*)d_in[16];

    // workspace layout: [msg | coord | cnt] zeroed, then the rest
    float* msg   = (float*)d_ws;                          // [NN,HD]
    float* coord = msg + (size_t)NN * HD;                 // [NN,3]
    int*   cnt   = (int*)(coord + (size_t)NN * 3);        // [NN]
    unsigned short* hb   = (unsigned short*)(cnt + NN);
    unsigned short* PWe1 = hb + (size_t)NN * HD;
    unsigned short* PWe2 = PWe1 + S_WE1;
    unsigned short* PWx1 = PWe2 + S_W4;
    unsigned short* PWh1 = PWx1 + S_W4;
    unsigned short* PWh2 = PWh1 + S_WH1;
    int*   perm   = (int*)(PWh2 + S_W4);                  // [NE]
    int*   cursor = perm + NE;                            // [NN]

    float* out_h = (float*)d_out;
    float* out_x = out_h + (size_t)NN * HD;

    hipMemsetAsync(d_ws, 0, (size_t)NN * (HD + 4) * sizeof(float), stream);
    egnn_prep_kernel<<<1024, 256, 0, stream>>>(h, We1, We2, Wx1, Wh1, Wh2,
                                               hb, PWe1, PWe2, PWx1, PWh1, PWh2);
    egnn_hist_kernel<<<NE / 256, 256, 0, stream>>>(ei, cnt);
    egnn_scan_kernel<<<1, 1024, 0, stream>>>(cnt, cursor);
    egnn_perm_kernel<<<NE / 256, 256, 0, stream>>>(ei, cursor, perm);
    egnn_edge_kernel<<<NE / 64, 256, 0, stream>>>(
        hb, x, ei, eattr, perm, PWe1, be1, PWe2, be2, PWx1, bx1, Wx2, bx2, msg, coord);
    egnn_node_kernel<<<(NN + 63) / 64, 256, 0, stream>>>(
        hb, h, x, fmask, PWh1, bh1, PWh2, bh2, msg, coord, out_h, out_x);
}